// Round 9
// baseline (828.008 us; speedup 1.0000x reference)
//
#include <hip/hip_runtime.h>
#include <hip/hip_bf16.h>

#define N_TOK 16384
#define DIM   128
#define JT     32      // K/V tile (j) per iteration (v7: halved for 4 blocks/CU)

// LDS row strides (shorts), unpadded + XOR swizzle (T2).
// kb rows (128 shorts = 16 segs of 16B): ss = seg ^ (row&7)  -> 8-lane phases
//   hit 8 distinct 16B bank-groups (conflict-free, m136 phase model).
// vb rows (32 shorts = 4 segs of 16B, 64B stride): ss = seg ^ ((row>>1)&3).
//   Bank-group g(row,ss) = (4*row + ss) mod 8 = 4*(row&1) + (seg ^ ((row>>1)&3))
//   -> over any 8 consecutive rows with fixed seg: {s,s^1,s^2,s^3} x {0,4} = 8
//   distinct groups; staging writes (4 lanes/row, segs 0-3) also distinct. OK.
#define KROW 128       // kbuf: 32 rows [kv][d]
#define VROW 32        // vbuf: 128 rows [d][kv]

using bf16x8 = __attribute__((ext_vector_type(8)))  short;  // 8 bf16 (MFMA A/B frag)
using f32x4  = __attribute__((ext_vector_type(4)))  float;
using f32x16 = __attribute__((ext_vector_type(16))) float;  // 32x32 MFMA C/D frag
using i32x4  = __attribute__((ext_vector_type(4)))  int;

static __device__ __forceinline__ unsigned short f2b(float f) {
    union { __hip_bfloat16 h; unsigned short u; } cv;
    cv.h = __float2bfloat16(f);   // RNE
    return cv.u;
}

static __device__ __forceinline__ bf16x8 load8f(const float* p) {
    float4 a = *reinterpret_cast<const float4*>(p);
    float4 b = *reinterpret_cast<const float4*>(p + 4);
    bf16x8 r;
    r[0] = (short)f2b(a.x); r[1] = (short)f2b(a.y);
    r[2] = (short)f2b(a.z); r[3] = (short)f2b(a.w);
    r[4] = (short)f2b(b.x); r[5] = (short)f2b(b.y);
    r[6] = (short)f2b(b.z); r[7] = (short)f2b(b.w);
    return r;
}

// ---------------------------------------------------------------------------
__global__ __launch_bounds__(256)
void marker_kernel(float* out, float val)
{
    int i = blockIdx.x * 256 + threadIdx.x;
    if (i < N_TOK * DIM) out[i] = val;
}

// ---------------------------------------------------------------------------
// QKV: Q = x@Wq^T, K = x@Wk^T, Vt = (x@Wv^T)^T.  fp32 in, bf16 out (ws).
// ---------------------------------------------------------------------------
__global__ __launch_bounds__(256)
void qkv_kernel(const float* __restrict__ x,
                const float* __restrict__ wq,
                const float* __restrict__ wk,
                const float* __restrict__ wv,
                unsigned short* __restrict__ Q,
                unsigned short* __restrict__ K,
                unsigned short* __restrict__ Vt)
{
    const int t = threadIdx.x;
    const int wave = t >> 6, lane = t & 63;
    const int ln = lane & 15, quad = lane >> 4, q8 = quad * 8;
    const int z = blockIdx.y;
    const float* W = (z == 0) ? wq : (z == 1) ? wk : wv;
    const int r0 = blockIdx.x * 64 + wave * 16;

    bf16x8 a[4];
#pragma unroll
    for (int ks = 0; ks < 4; ++ks)
        a[ks] = load8f(&x[(size_t)(r0 + ln) * DIM + ks * 32 + q8]);

    f32x4 acc[8];
#pragma unroll
    for (int nt = 0; nt < 8; ++nt) acc[nt] = f32x4{0.f, 0.f, 0.f, 0.f};

#pragma unroll
    for (int nt = 0; nt < 8; ++nt)
#pragma unroll
        for (int ks = 0; ks < 4; ++ks) {
            bf16x8 b = load8f(&W[(size_t)(nt * 16 + ln) * DIM + ks * 32 + q8]);
            acc[nt] = __builtin_amdgcn_mfma_f32_16x16x32_bf16(a[ks], b, acc[nt], 0, 0, 0);
        }

#pragma unroll
    for (int nt = 0; nt < 8; ++nt) {
        const int col = nt * 16 + ln;
        if (z == 2) {
            ushort4 v4;
            v4.x = f2b(acc[nt][0]); v4.y = f2b(acc[nt][1]);
            v4.z = f2b(acc[nt][2]); v4.w = f2b(acc[nt][3]);
            *reinterpret_cast<ushort4*>(&Vt[(size_t)col * N_TOK + r0 + quad * 4]) = v4;
        } else {
            unsigned short* dst = (z == 0) ? Q : K;
#pragma unroll
            for (int r = 0; r < 4; ++r)
                dst[(size_t)(r0 + quad * 4 + r) * DIM + col] = f2b(acc[nt][r]);
        }
    }
}

// ---------------------------------------------------------------------------
// Flash attention v7: v6's 32x32 swapped-QK^T / in-register softmax, with
// JT=32 tiles to shrink LDS 66.5->33.5 KB => 4 blocks/CU (16 waves/CU,
// 4 waves/SIMD), fed by nsplit=8 (grid 1024 = 4/CU exactly).
// Tiles/block stays 64 (jspan 2048 / JT 32) -> barrier count unchanged;
// each barrier fences half the work and 2x blocks interleave per SIMD.
//
// Swapped QK^T: S^T = mfma_32x32x16(A=K, B=Q): D[m=kv][n=q].
// C-layout (m74/m101): col=lane&31 -> q; row=crow(reg,hi)=(reg&3)+8*(reg>>2)+4*hi.
// Lane owns P[q=lane&31][kv=crow] (half the tile's kv; partner lane^32 has
// the rest).  Softmax is pure register math (fixed-offset exp2, no max).
//
// P -> PV A-frag (A[m=q][k=16*kt+8*hi+j], k=8g+4h'+i): frag(kt) gets
// (h'=0,g=2kt+hi) then (h'=1,g=2kt+hi); one shfl_xor(32) per dword pair.
//
// PV: mfma_32x32x16(A=pa[kt], B=V): B[n=d=32nt+q31][k=kv] from vb[d][kv].
// ---------------------------------------------------------------------------
__global__ __launch_bounds__(256, 4)
void flash_kernel(const unsigned short* __restrict__ Q,
                  const unsigned short* __restrict__ K,
                  const unsigned short* __restrict__ Vt,
                  const unsigned int* __restrict__ u32,
                  int jspan,
                  float* __restrict__ pO, float* __restrict__ pl,
                  float* __restrict__ out)
{
    __shared__ __align__(16) unsigned short kb[2][JT * KROW];   // 16 KB
    __shared__ __align__(16) unsigned short vb[2][DIM * VROW];  // 16 KB
    __shared__ __align__(16) int   ub[2][JT];                   // 256 B
    __shared__ __align__(16) float lbuf[4][32];                 // 512 B -> 33.5 KB

    const int t = threadIdx.x;
    const int wave = t >> 6, lane = t & 63;
    const int q31 = lane & 31, hi = lane >> 5;
    const int r0w = blockIdx.x * 128 + wave * 32;    // this wave's q-base
    const int split = blockIdx.y;
    const int j0 = split * jspan;
    const int j1 = j0 + jspan;

    const float lscale = 1.4426950408889634f * 0.08838834764831845f; // log2(e)/sqrt(128)
    const float cbias  = 5.0f * 1.4426950408889634f - 16.0f;         // same-user
    const float cnob   = -16.0f;                                     // different user

    // uid dtype sniff (uniform verdict on every thread)
    bool i64 = true;
    for (int k = 0; k < 64; ++k) i64 = i64 && (u32[2 * k + 1] == 0u);

    // Q fragments: B[n=q31][k = dt*16 + hi*8 + j]
    bf16x8 qf[8];
#pragma unroll
    for (int dt = 0; dt < 8; ++dt)
        qf[dt] = *reinterpret_cast<const bf16x8*>(
            &Q[(size_t)(r0w + q31) * DIM + dt * 16 + hi * 8]);

    const int uq = (int)(i64 ? u32[2 * (r0w + q31)] : u32[r0w + q31]);

    f32x16 o[4];
#pragma unroll
    for (int nt = 0; nt < 4; ++nt)
#pragma unroll
        for (int r = 0; r < 16; ++r) o[nt][r] = 0.f;
    float lsum = 0.f;

    // ---- prologue: stage tile j0 into buffer 0 (swizzled dest) ----
    {
#pragma unroll
        for (int p = 0; p < 2; ++p) {
            int slot = p * 256 + t;                  // 512 chunks: 32 rows x 16 segs
            int row = slot >> 4, seg = slot & 15;
            int ss = seg ^ (row & 7);
            *reinterpret_cast<uint4*>(&kb[0][row * KROW + ss * 8]) =
                *reinterpret_cast<const uint4*>(&K[(size_t)(j0 + row) * DIM + seg * 8]);
        }
#pragma unroll
        for (int p = 0; p < 2; ++p) {
            int slot = p * 256 + t;                  // 512 chunks: 128 rows x 4 segs
            int row = slot >> 2, seg = slot & 3;
            int ss = seg ^ ((row >> 1) & 3);
            *reinterpret_cast<uint4*>(&vb[0][row * VROW + ss * 8]) =
                *reinterpret_cast<const uint4*>(&Vt[(size_t)row * N_TOK + j0 + seg * 8]);
        }
        if (t < JT) {
            int i = j0 + t;
            ub[0][t] = (int)(i64 ? u32[2 * i] : u32[i]);
        }
    }
    __syncthreads();

    int c = 0;
    for (int j = j0; j < j1; j += JT) {
        int jn = j + JT;
        if (jn >= j1) jn = j0;   // dummy wrap on last iter

        // ---- prefetch next tile into regs ----
        uint4 kreg[2];
#pragma unroll
        for (int p = 0; p < 2; ++p) {
            int slot = p * 256 + t;
            int row = slot >> 4, seg = slot & 15;
            kreg[p] = *reinterpret_cast<const uint4*>(&K[(size_t)(jn + row) * DIM + seg * 8]);
        }
        uint4 vreg[2];
#pragma unroll
        for (int p = 0; p < 2; ++p) {
            int slot = p * 256 + t;
            int row = slot >> 2, seg = slot & 3;
            vreg[p] = *reinterpret_cast<const uint4*>(&Vt[(size_t)row * N_TOK + jn + seg * 8]);
        }
        int ureg = 0;
        if (t < JT) ureg = (int)(i64 ? u32[2 * (jn + t)] : u32[jn + t]);

        // ---- swapped QK^T: S^T[kv=0..31][q] accumulated over 8 dt ----
        f32x16 sv;
#pragma unroll
        for (int r = 0; r < 16; ++r) sv[r] = 0.f;
        __builtin_amdgcn_s_setprio(1);
#pragma unroll
        for (int dt = 0; dt < 8; ++dt) {
            int seg = (dt * 2 + hi) ^ (q31 & 7);
            bf16x8 k0 = *reinterpret_cast<const bf16x8*>(&kb[c][q31 * KROW + seg * 8]);
            sv = __builtin_amdgcn_mfma_f32_32x32x16_bf16(k0, qf[dt], sv, 0, 0, 0);
        }
        __builtin_amdgcn_s_setprio(0);

        // ---- softmax + pack + half-wave exchange -> pa[2] ----
        bf16x8 pa[2];
        {
            i32x4 ukg[4];
#pragma unroll
            for (int g = 0; g < 4; ++g)
                ukg[g] = *reinterpret_cast<const i32x4*>(&ub[c][8 * g + 4 * hi]);

            unsigned int dw[4][2];
#pragma unroll
            for (int g = 0; g < 4; ++g) {
                float v0 = __builtin_fmaf(sv[4 * g + 0], lscale, (uq == ukg[g][0]) ? cbias : cnob);
                float v1 = __builtin_fmaf(sv[4 * g + 1], lscale, (uq == ukg[g][1]) ? cbias : cnob);
                float v2 = __builtin_fmaf(sv[4 * g + 2], lscale, (uq == ukg[g][2]) ? cbias : cnob);
                float v3 = __builtin_fmaf(sv[4 * g + 3], lscale, (uq == ukg[g][3]) ? cbias : cnob);
                float p0 = exp2f(v0), p1 = exp2f(v1), p2 = exp2f(v2), p3 = exp2f(v3);
                lsum += (p0 + p1) + (p2 + p3);
                dw[g][0] = (unsigned int)f2b(p0) | ((unsigned int)f2b(p1) << 16);
                dw[g][1] = (unsigned int)f2b(p2) | ((unsigned int)f2b(p3) << 16);
            }

#pragma unroll
            for (int kt = 0; kt < 2; ++kt) {
                unsigned int s0d = hi ? dw[2 * kt][0] : dw[2 * kt + 1][0];
                unsigned int s1d = hi ? dw[2 * kt][1] : dw[2 * kt + 1][1];
                unsigned int r0d = (unsigned int)__shfl_xor((int)s0d, 32, 64);
                unsigned int r1d = (unsigned int)__shfl_xor((int)s1d, 32, 64);
                unsigned int k0d = hi ? dw[2 * kt + 1][0] : dw[2 * kt][0];
                unsigned int k1d = hi ? dw[2 * kt + 1][1] : dw[2 * kt][1];
                union { unsigned int u[4]; bf16x8 v; } pu;
                pu.u[0] = hi ? r0d : k0d;
                pu.u[1] = hi ? r1d : k1d;
                pu.u[2] = hi ? k0d : r0d;
                pu.u[3] = hi ? k1d : r1d;
                pa[kt] = pu.v;
            }
        }

        // ---- write prefetched K/u into idle buffer ----
#pragma unroll
        for (int p = 0; p < 2; ++p) {
            int slot = p * 256 + t;
            int row = slot >> 4, seg = slot & 15;
            int ss = seg ^ (row & 7);
            *reinterpret_cast<uint4*>(&kb[c ^ 1][row * KROW + ss * 8]) = kreg[p];
        }
        if (t < JT) ub[c ^ 1][t] = ureg;

        // ---- PV: O[q][d] += P @ V  (B[n=d][k=kv] from vb rows) ----
        __builtin_amdgcn_s_setprio(1);
#pragma unroll
        for (int nt = 0; nt < 4; ++nt) {
            int row = nt * 32 + q31;
#pragma unroll
            for (int kt = 0; kt < 2; ++kt) {
                int seg = (kt * 2 + hi) ^ ((row >> 1) & 3);
                bf16x8 b = *reinterpret_cast<const bf16x8*>(&vb[c][row * VROW + seg * 8]);
                o[nt] = __builtin_amdgcn_mfma_f32_32x32x16_bf16(pa[kt], b, o[nt], 0, 0, 0);
            }
        }
        __builtin_amdgcn_s_setprio(0);

        // ---- write prefetched V into idle buffer ----
#pragma unroll
        for (int p = 0; p < 2; ++p) {
            int slot = p * 256 + t;
            int row = slot >> 2, seg = slot & 3;
            int ss = seg ^ ((row >> 1) & 3);
            *reinterpret_cast<uint4*>(&vb[c ^ 1][row * VROW + ss * 8]) = vreg[p];
        }

        __syncthreads();   // single barrier per tile
        c ^= 1;
    }

    // ---- epilogue ----
    lsum += __shfl_xor(lsum, 32, 64);   // combine the two k-halves of q=q31

    if (out != nullptr) {
        bool lbad = !(lsum > 0.f) || !(lsum < 3.0e38f);
        float inv = 1.0f / lsum;
        if (hi == 0) lbuf[wave][q31] = lbad ? -1.0f : inv;
        __syncthreads();
        f32x4 ivg[4];
#pragma unroll
        for (int g = 0; g < 4; ++g)
            ivg[g] = *reinterpret_cast<const f32x4*>(&lbuf[wave][8 * g + 4 * hi]);
#pragma unroll
        for (int nt = 0; nt < 4; ++nt)
#pragma unroll
            for (int g = 0; g < 4; ++g)
#pragma unroll
                for (int i = 0; i < 4; ++i) {
                    int row = r0w + 8 * g + 4 * hi + i;
                    float iv = ivg[g][i];
                    float v = o[nt][4 * g + i] * iv;
                    if (v != v) v = 12345.0f;
                    if (iv < 0.f) v = 23456.0f;
                    out[(size_t)row * DIM + nt * 32 + q31] = v;
                }
    } else {
        const size_t base = (size_t)split * N_TOK;
        if (hi == 0) pl[base + r0w + q31] = lsum;
#pragma unroll
        for (int nt = 0; nt < 4; ++nt)
#pragma unroll
            for (int g = 0; g < 4; ++g)
#pragma unroll
                for (int i = 0; i < 4; ++i) {
                    int row = r0w + 8 * g + 4 * hi + i;
                    pO[(base + row) * DIM + nt * 32 + q31] = o[nt][4 * g + i];
                }
    }
}

// ---------------------------------------------------------------------------
// Merge: out[row] = (sum_s pO[s][row]) / (sum_s pl[s][row]).
// ---------------------------------------------------------------------------
__global__ __launch_bounds__(256)
void merge_kernel(const float* __restrict__ pO, const float* __restrict__ pl,
                  float* __restrict__ out, int ns)
{
    const int t = threadIdx.x;
    const int wave = t >> 6, lane = t & 63;
    const int row = blockIdx.x * 4 + wave;
    const int c = lane * 2;

    float l = 0.f;
    for (int s = 0; s < ns; ++s) l += pl[(size_t)s * N_TOK + row];
    bool lbad = !(l > 0.f) || !(l < 3.0e38f);
    float inv = 1.0f / l;

    float a0 = 0.f, a1 = 0.f;
    for (int s = 0; s < ns; ++s) {
        const float2 v = *reinterpret_cast<const float2*>(
            &pO[((size_t)s * N_TOK + row) * DIM + c]);
        a0 += v.x; a1 += v.y;
    }
    float v0 = a0 * inv, v1 = a1 * inv;
    if (v0 != v0) v0 = 12345.0f;
    if (v1 != v1) v1 = 12345.0f;
    if (lbad) { v0 = 23456.0f; v1 = 23456.0f; }
    float2 res; res.x = v0; res.y = v1;
    *reinterpret_cast<float2*>(&out[(size_t)row * DIM + c]) = res;
}

// ---------------------------------------------------------------------------
extern "C" void kernel_launch(void* const* d_in, const int* in_sizes, int n_in,
                              void* d_out, int out_size, void* d_ws, size_t ws_size,
                              hipStream_t stream)
{
    float* out = (float*)d_out;

    bool ok = (n_in == 5) &&
              in_sizes[0] == N_TOK * DIM && in_sizes[1] == N_TOK &&
              in_sizes[2] == DIM * DIM && in_sizes[3] == DIM * DIM &&
              in_sizes[4] == DIM * DIM && out_size == N_TOK * DIM;
    if (!ok) { marker_kernel<<<8192, 256, 0, stream>>>(out, 5555.f); return; }

    const float*        xf  = (const float*)d_in[0];
    const unsigned int* u32 = (const unsigned int*)d_in[1];
    const float*        wqf = (const float*)d_in[2];
    const float*        wkf = (const float*)d_in[3];
    const float*        wvf = (const float*)d_in[4];

    char* ws = (char*)d_ws;
    size_t off = 0;
    unsigned short* Q  = (unsigned short*)(ws + off); off += (size_t)N_TOK * DIM * 2;  // 4 MB
    unsigned short* K  = (unsigned short*)(ws + off); off += (size_t)N_TOK * DIM * 2;  // 4 MB
    unsigned short* Vt = (unsigned short*)(ws + off); off += (size_t)N_TOK * DIM * 2;  // 4 MB

    if (ws_size < off) { marker_kernel<<<8192, 256, 0, stream>>>(out, 4444.f); return; }

    // v7: nsplit=8 -> grid (128,8)=1024 blocks = 4 blocks/CU (LDS 33.5 KB).
    // Fallbacks keep correctness when ws is small.
    const size_t per_split = (size_t)N_TOK * DIM * 4 + (size_t)N_TOK * 4;
    int nsplit = 1;
    if (ws_size >= off + 8 * per_split)      nsplit = 8;
    else if (ws_size >= off + 4 * per_split) nsplit = 4;
    else if (ws_size >= off + 2 * per_split) nsplit = 2;

    qkv_kernel<<<dim3(N_TOK / 64, 3), 256, 0, stream>>>(xf, wqf, wkf, wvf, Q, K, Vt);

    if (nsplit >= 2) {
        float* pO = (float*)(ws + off);
        float* pl = (float*)(ws + off + (size_t)nsplit * N_TOK * DIM * 4);
        flash_kernel<<<dim3(N_TOK / 128, nsplit), 256, 0, stream>>>(
            Q, K, Vt, u32, N_TOK / nsplit, pO, pl, nullptr);
        merge_kernel<<<N_TOK / 4, 256, 0, stream>>>(pO, pl, out, nsplit);
    } else {
        flash_kernel<<<dim3(N_TOK / 128, 1), 256, 0, stream>>>(
            Q, K, Vt, u32, N_TOK, nullptr, nullptr, out);
    }
}

// Round 10
// 375.278 us; speedup vs baseline: 2.2064x; 2.2064x over previous
//
#include <hip/hip_runtime.h>
#include <hip/hip_bf16.h>

#define N_TOK 16384
#define DIM   128
#define JT     32      // K/V tile (j) per iteration

// LDS row strides (shorts), unpadded + XOR swizzle (T2).
// kb rows (128 shorts = 16 segs of 16B): ss = seg ^ (row&7).
// vb rows (32 shorts = 4 segs of 16B): ss = seg ^ ((row>>1)&3); bank-group
//   g = 4*(row&1) + ss -> 8 distinct groups over any 8-row/fixed-seg phase.
#define KROW 128       // kbuf: 32 rows [kv][d]
#define VROW 32        // vbuf: 128 rows [d][kv]

using bf16x8 = __attribute__((ext_vector_type(8)))  short;  // 8 bf16 (MFMA A/B frag)
using f32x4  = __attribute__((ext_vector_type(4)))  float;
using f32x16 = __attribute__((ext_vector_type(16))) float;  // 32x32 MFMA C/D frag
using i32x4  = __attribute__((ext_vector_type(4)))  int;

static __device__ __forceinline__ unsigned short f2b(float f) {
    union { __hip_bfloat16 h; unsigned short u; } cv;
    cv.h = __float2bfloat16(f);   // RNE
    return cv.u;
}

static __device__ __forceinline__ bf16x8 load8f(const float* p) {
    float4 a = *reinterpret_cast<const float4*>(p);
    float4 b = *reinterpret_cast<const float4*>(p + 4);
    bf16x8 r;
    r[0] = (short)f2b(a.x); r[1] = (short)f2b(a.y);
    r[2] = (short)f2b(a.z); r[3] = (short)f2b(a.w);
    r[4] = (short)f2b(b.x); r[5] = (short)f2b(b.y);
    r[6] = (short)f2b(b.z); r[7] = (short)f2b(b.w);
    return r;
}

// ---------------------------------------------------------------------------
__global__ __launch_bounds__(256)
void marker_kernel(float* out, float val)
{
    int i = blockIdx.x * 256 + threadIdx.x;
    if (i < N_TOK * DIM) out[i] = val;
}

// ---------------------------------------------------------------------------
// QKV: Q = x@Wq^T, K = x@Wk^T, Vt = (x@Wv^T)^T.  fp32 in, bf16 out (ws).
// ---------------------------------------------------------------------------
__global__ __launch_bounds__(256)
void qkv_kernel(const float* __restrict__ x,
                const float* __restrict__ wq,
                const float* __restrict__ wk,
                const float* __restrict__ wv,
                unsigned short* __restrict__ Q,
                unsigned short* __restrict__ K,
                unsigned short* __restrict__ Vt)
{
    const int t = threadIdx.x;
    const int wave = t >> 6, lane = t & 63;
    const int ln = lane & 15, quad = lane >> 4, q8 = quad * 8;
    const int z = blockIdx.y;
    const float* W = (z == 0) ? wq : (z == 1) ? wk : wv;
    const int r0 = blockIdx.x * 64 + wave * 16;

    bf16x8 a[4];
#pragma unroll
    for (int ks = 0; ks < 4; ++ks)
        a[ks] = load8f(&x[(size_t)(r0 + ln) * DIM + ks * 32 + q8]);

    f32x4 acc[8];
#pragma unroll
    for (int nt = 0; nt < 8; ++nt) acc[nt] = f32x4{0.f, 0.f, 0.f, 0.f};

#pragma unroll
    for (int nt = 0; nt < 8; ++nt)
#pragma unroll
        for (int ks = 0; ks < 4; ++ks) {
            bf16x8 b = load8f(&W[(size_t)(nt * 16 + ln) * DIM + ks * 32 + q8]);
            acc[nt] = __builtin_amdgcn_mfma_f32_16x16x32_bf16(a[ks], b, acc[nt], 0, 0, 0);
        }

#pragma unroll
    for (int nt = 0; nt < 8; ++nt) {
        const int col = nt * 16 + ln;
        if (z == 2) {
            ushort4 v4;
            v4.x = f2b(acc[nt][0]); v4.y = f2b(acc[nt][1]);
            v4.z = f2b(acc[nt][2]); v4.w = f2b(acc[nt][3]);
            *reinterpret_cast<ushort4*>(&Vt[(size_t)col * N_TOK + r0 + quad * 4]) = v4;
        } else {
            unsigned short* dst = (z == 0) ? Q : K;
#pragma unroll
            for (int r = 0; r < 4; ++r)
                dst[(size_t)(r0 + quad * 4 + r) * DIM + col] = f2b(acc[nt][r]);
        }
    }
}

// ---------------------------------------------------------------------------
// Flash attention v8: v7's 32x32 swapped-QK^T / in-register softmax / JT=32,
// with the register budget done RIGHT this time:
//   live state ~150 VGPR (o[4]x16=64, qf[8]=32, sv=16, staging 16, pa/dw ~16)
//   -> 3 waves/SIMD is the max (512/3=170).  __launch_bounds__(256,3) caps
//   the allocator at 170 (R9's (256,4) forced 64 -> total scratch spill,
//   2.1 GB of HBM traffic).
// Grid sized for EXACTLY one residency round at 3 blocks/CU: 768 blocks =
// (128 x-blocks, 6 splits).  16384/6 is not JT-aligned, so splits are
// uneven-clamped: jspan=2752 (86 tiles) for splits 0-4, split 5 clamps to
// j1=16384 (2624 = 82 tiles).  All boundaries are JT-multiples; <1% skew.
//
// Swapped QK^T: S^T = mfma_32x32x16(A=K, B=Q): lane owns P[q=lane&31][kv=crow],
// crow=(reg&3)+8*(reg>>2)+4*hi (m74/m101).  Softmax = fixed-offset exp2 in
// registers.  P->PV A-frag via one shfl_xor(32) per dword pair.
// PV: B[n=d=32nt+q31][k=kv] from vb[d][kv] rows.
// ---------------------------------------------------------------------------
__global__ __launch_bounds__(256, 3)
void flash_kernel(const unsigned short* __restrict__ Q,
                  const unsigned short* __restrict__ K,
                  const unsigned short* __restrict__ Vt,
                  const unsigned int* __restrict__ u32,
                  int jspan,
                  float* __restrict__ pO, float* __restrict__ pl,
                  float* __restrict__ out)
{
    __shared__ __align__(16) unsigned short kb[2][JT * KROW];   // 16 KB
    __shared__ __align__(16) unsigned short vb[2][DIM * VROW];  // 16 KB
    __shared__ __align__(16) int   ub[2][JT];                   // 256 B
    __shared__ __align__(16) float lbuf[4][32];                 // 512 B -> 33.5 KB

    const int t = threadIdx.x;
    const int wave = t >> 6, lane = t & 63;
    const int q31 = lane & 31, hi = lane >> 5;
    const int r0w = blockIdx.x * 128 + wave * 32;    // this wave's q-base
    const int split = blockIdx.y;
    const int j0 = split * jspan;
    int j1 = j0 + jspan;
    if (j1 > N_TOK) j1 = N_TOK;                      // uneven last split

    const float lscale = 1.4426950408889634f * 0.08838834764831845f; // log2(e)/sqrt(128)
    const float cbias  = 5.0f * 1.4426950408889634f - 16.0f;         // same-user
    const float cnob   = -16.0f;                                     // different user

    // uid dtype sniff (uniform verdict on every thread)
    bool i64 = true;
    for (int k = 0; k < 64; ++k) i64 = i64 && (u32[2 * k + 1] == 0u);

    // Q fragments: B[n=q31][k = dt*16 + hi*8 + j]
    bf16x8 qf[8];
#pragma unroll
    for (int dt = 0; dt < 8; ++dt)
        qf[dt] = *reinterpret_cast<const bf16x8*>(
            &Q[(size_t)(r0w + q31) * DIM + dt * 16 + hi * 8]);

    const int uq = (int)(i64 ? u32[2 * (r0w + q31)] : u32[r0w + q31]);

    f32x16 o[4];
#pragma unroll
    for (int nt = 0; nt < 4; ++nt)
#pragma unroll
        for (int r = 0; r < 16; ++r) o[nt][r] = 0.f;
    float lsum = 0.f;

    // ---- prologue: stage tile j0 into buffer 0 (swizzled dest) ----
    {
#pragma unroll
        for (int p = 0; p < 2; ++p) {
            int slot = p * 256 + t;                  // 512 chunks: 32 rows x 16 segs
            int row = slot >> 4, seg = slot & 15;
            int ss = seg ^ (row & 7);
            *reinterpret_cast<uint4*>(&kb[0][row * KROW + ss * 8]) =
                *reinterpret_cast<const uint4*>(&K[(size_t)(j0 + row) * DIM + seg * 8]);
        }
#pragma unroll
        for (int p = 0; p < 2; ++p) {
            int slot = p * 256 + t;                  // 512 chunks: 128 rows x 4 segs
            int row = slot >> 2, seg = slot & 3;
            int ss = seg ^ ((row >> 1) & 3);
            *reinterpret_cast<uint4*>(&vb[0][row * VROW + ss * 8]) =
                *reinterpret_cast<const uint4*>(&Vt[(size_t)row * N_TOK + j0 + seg * 8]);
        }
        if (t < JT) {
            int i = j0 + t;
            ub[0][t] = (int)(i64 ? u32[2 * i] : u32[i]);
        }
    }
    __syncthreads();

    int c = 0;
    for (int j = j0; j < j1; j += JT) {
        int jn = j + JT;
        if (jn >= j1) jn = j0;   // dummy wrap on last iter

        // ---- prefetch next tile into regs ----
        uint4 kreg[2];
#pragma unroll
        for (int p = 0; p < 2; ++p) {
            int slot = p * 256 + t;
            int row = slot >> 4, seg = slot & 15;
            kreg[p] = *reinterpret_cast<const uint4*>(&K[(size_t)(jn + row) * DIM + seg * 8]);
        }
        uint4 vreg[2];
#pragma unroll
        for (int p = 0; p < 2; ++p) {
            int slot = p * 256 + t;
            int row = slot >> 2, seg = slot & 3;
            vreg[p] = *reinterpret_cast<const uint4*>(&Vt[(size_t)row * N_TOK + jn + seg * 8]);
        }
        int ureg = 0;
        if (t < JT) ureg = (int)(i64 ? u32[2 * (jn + t)] : u32[jn + t]);

        // ---- swapped QK^T: S^T[kv=0..31][q] accumulated over 8 dt ----
        f32x16 sv;
#pragma unroll
        for (int r = 0; r < 16; ++r) sv[r] = 0.f;
        __builtin_amdgcn_s_setprio(1);
#pragma unroll
        for (int dt = 0; dt < 8; ++dt) {
            int seg = (dt * 2 + hi) ^ (q31 & 7);
            bf16x8 k0 = *reinterpret_cast<const bf16x8*>(&kb[c][q31 * KROW + seg * 8]);
            sv = __builtin_amdgcn_mfma_f32_32x32x16_bf16(k0, qf[dt], sv, 0, 0, 0);
        }
        __builtin_amdgcn_s_setprio(0);

        // ---- softmax + pack + half-wave exchange -> pa[2] ----
        bf16x8 pa[2];
        {
            i32x4 ukg[4];
#pragma unroll
            for (int g = 0; g < 4; ++g)
                ukg[g] = *reinterpret_cast<const i32x4*>(&ub[c][8 * g + 4 * hi]);

            unsigned int dw[4][2];
#pragma unroll
            for (int g = 0; g < 4; ++g) {
                float v0 = __builtin_fmaf(sv[4 * g + 0], lscale, (uq == ukg[g][0]) ? cbias : cnob);
                float v1 = __builtin_fmaf(sv[4 * g + 1], lscale, (uq == ukg[g][1]) ? cbias : cnob);
                float v2 = __builtin_fmaf(sv[4 * g + 2], lscale, (uq == ukg[g][2]) ? cbias : cnob);
                float v3 = __builtin_fmaf(sv[4 * g + 3], lscale, (uq == ukg[g][3]) ? cbias : cnob);
                float p0 = exp2f(v0), p1 = exp2f(v1), p2 = exp2f(v2), p3 = exp2f(v3);
                lsum += (p0 + p1) + (p2 + p3);
                dw[g][0] = (unsigned int)f2b(p0) | ((unsigned int)f2b(p1) << 16);
                dw[g][1] = (unsigned int)f2b(p2) | ((unsigned int)f2b(p3) << 16);
            }

#pragma unroll
            for (int kt = 0; kt < 2; ++kt) {
                unsigned int s0d = hi ? dw[2 * kt][0] : dw[2 * kt + 1][0];
                unsigned int s1d = hi ? dw[2 * kt][1] : dw[2 * kt + 1][1];
                unsigned int r0d = (unsigned int)__shfl_xor((int)s0d, 32, 64);
                unsigned int r1d = (unsigned int)__shfl_xor((int)s1d, 32, 64);
                unsigned int k0d = hi ? dw[2 * kt + 1][0] : dw[2 * kt][0];
                unsigned int k1d = hi ? dw[2 * kt + 1][1] : dw[2 * kt][1];
                union { unsigned int u[4]; bf16x8 v; } pu;
                pu.u[0] = hi ? r0d : k0d;
                pu.u[1] = hi ? r1d : k1d;
                pu.u[2] = hi ? k0d : r0d;
                pu.u[3] = hi ? k1d : r1d;
                pa[kt] = pu.v;
            }
        }

        // ---- write prefetched K/u into idle buffer ----
#pragma unroll
        for (int p = 0; p < 2; ++p) {
            int slot = p * 256 + t;
            int row = slot >> 4, seg = slot & 15;
            int ss = seg ^ (row & 7);
            *reinterpret_cast<uint4*>(&kb[c ^ 1][row * KROW + ss * 8]) = kreg[p];
        }
        if (t < JT) ub[c ^ 1][t] = ureg;

        // ---- PV: O[q][d] += P @ V  (B[n=d][k=kv] from vb rows) ----
        __builtin_amdgcn_s_setprio(1);
#pragma unroll
        for (int nt = 0; nt < 4; ++nt) {
            int row = nt * 32 + q31;
#pragma unroll
            for (int kt = 0; kt < 2; ++kt) {
                int seg = (kt * 2 + hi) ^ ((row >> 1) & 3);
                bf16x8 b = *reinterpret_cast<const bf16x8*>(&vb[c][row * VROW + seg * 8]);
                o[nt] = __builtin_amdgcn_mfma_f32_32x32x16_bf16(pa[kt], b, o[nt], 0, 0, 0);
            }
        }
        __builtin_amdgcn_s_setprio(0);

        // ---- write prefetched V into idle buffer ----
#pragma unroll
        for (int p = 0; p < 2; ++p) {
            int slot = p * 256 + t;
            int row = slot >> 2, seg = slot & 3;
            int ss = seg ^ ((row >> 1) & 3);
            *reinterpret_cast<uint4*>(&vb[c ^ 1][row * VROW + ss * 8]) = vreg[p];
        }

        __syncthreads();   // single barrier per tile
        c ^= 1;
    }

    // ---- epilogue ----
    lsum += __shfl_xor(lsum, 32, 64);   // combine the two k-halves of q=q31

    if (out != nullptr) {
        bool lbad = !(lsum > 0.f) || !(lsum < 3.0e38f);
        float inv = 1.0f / lsum;
        if (hi == 0) lbuf[wave][q31] = lbad ? -1.0f : inv;
        __syncthreads();
        f32x4 ivg[4];
#pragma unroll
        for (int g = 0; g < 4; ++g)
            ivg[g] = *reinterpret_cast<const f32x4*>(&lbuf[wave][8 * g + 4 * hi]);
#pragma unroll
        for (int nt = 0; nt < 4; ++nt)
#pragma unroll
            for (int g = 0; g < 4; ++g)
#pragma unroll
                for (int i = 0; i < 4; ++i) {
                    int row = r0w + 8 * g + 4 * hi + i;
                    float iv = ivg[g][i];
                    float v = o[nt][4 * g + i] * iv;
                    if (v != v) v = 12345.0f;
                    if (iv < 0.f) v = 23456.0f;
                    out[(size_t)row * DIM + nt * 32 + q31] = v;
                }
    } else {
        const size_t base = (size_t)split * N_TOK;
        if (hi == 0) pl[base + r0w + q31] = lsum;
#pragma unroll
        for (int nt = 0; nt < 4; ++nt)
#pragma unroll
            for (int g = 0; g < 4; ++g)
#pragma unroll
                for (int i = 0; i < 4; ++i) {
                    int row = r0w + 8 * g + 4 * hi + i;
                    pO[(base + row) * DIM + nt * 32 + q31] = o[nt][4 * g + i];
                }
    }
}

// ---------------------------------------------------------------------------
// Merge: out[row] = (sum_s pO[s][row]) / (sum_s pl[s][row]).
// ---------------------------------------------------------------------------
__global__ __launch_bounds__(256)
void merge_kernel(const float* __restrict__ pO, const float* __restrict__ pl,
                  float* __restrict__ out, int ns)
{
    const int t = threadIdx.x;
    const int wave = t >> 6, lane = t & 63;
    const int row = blockIdx.x * 4 + wave;
    const int c = lane * 2;

    float l = 0.f;
    for (int s = 0; s < ns; ++s) l += pl[(size_t)s * N_TOK + row];
    bool lbad = !(l > 0.f) || !(l < 3.0e38f);
    float inv = 1.0f / l;

    float a0 = 0.f, a1 = 0.f;
    for (int s = 0; s < ns; ++s) {
        const float2 v = *reinterpret_cast<const float2*>(
            &pO[((size_t)s * N_TOK + row) * DIM + c]);
        a0 += v.x; a1 += v.y;
    }
    float v0 = a0 * inv, v1 = a1 * inv;
    if (v0 != v0) v0 = 12345.0f;
    if (v1 != v1) v1 = 12345.0f;
    if (lbad) { v0 = 23456.0f; v1 = 23456.0f; }
    float2 res; res.x = v0; res.y = v1;
    *reinterpret_cast<float2*>(&out[(size_t)row * DIM + c]) = res;
}

// ---------------------------------------------------------------------------
extern "C" void kernel_launch(void* const* d_in, const int* in_sizes, int n_in,
                              void* d_out, int out_size, void* d_ws, size_t ws_size,
                              hipStream_t stream)
{
    float* out = (float*)d_out;

    bool ok = (n_in == 5) &&
              in_sizes[0] == N_TOK * DIM && in_sizes[1] == N_TOK &&
              in_sizes[2] == DIM * DIM && in_sizes[3] == DIM * DIM &&
              in_sizes[4] == DIM * DIM && out_size == N_TOK * DIM;
    if (!ok) { marker_kernel<<<8192, 256, 0, stream>>>(out, 5555.f); return; }

    const float*        xf  = (const float*)d_in[0];
    const unsigned int* u32 = (const unsigned int*)d_in[1];
    const float*        wqf = (const float*)d_in[2];
    const float*        wkf = (const float*)d_in[3];
    const float*        wvf = (const float*)d_in[4];

    char* ws = (char*)d_ws;
    size_t off = 0;
    unsigned short* Q  = (unsigned short*)(ws + off); off += (size_t)N_TOK * DIM * 2;  // 4 MB
    unsigned short* K  = (unsigned short*)(ws + off); off += (size_t)N_TOK * DIM * 2;  // 4 MB
    unsigned short* Vt = (unsigned short*)(ws + off); off += (size_t)N_TOK * DIM * 2;  // 4 MB

    if (ws_size < off) { marker_kernel<<<8192, 256, 0, stream>>>(out, 4444.f); return; }

    // v8: 6 uneven splits -> grid (128,6)=768 blocks = exactly 3 blocks/CU
    // (one residency round at the 3-waves/SIMD register budget).
    // jspan=2752 (86 tiles); split 5 clamps to 16384 (82 tiles).
    const size_t per_split = (size_t)N_TOK * DIM * 4 + (size_t)N_TOK * 4;
    int nsplit = 1;
    int jspan = N_TOK;
    if (ws_size >= off + 6 * per_split)      { nsplit = 6; jspan = 2752; }
    else if (ws_size >= off + 4 * per_split) { nsplit = 4; jspan = 4096; }
    else if (ws_size >= off + 2 * per_split) { nsplit = 2; jspan = 8192; }

    qkv_kernel<<<dim3(N_TOK / 64, 3), 256, 0, stream>>>(xf, wqf, wkf, wvf, Q, K, Vt);

    if (nsplit >= 2) {
        float* pO = (float*)(ws + off);
        float* pl = (float*)(ws + off + (size_t)nsplit * N_TOK * DIM * 4);
        flash_kernel<<<dim3(N_TOK / 128, nsplit), 256, 0, stream>>>(
            Q, K, Vt, u32, jspan, pO, pl, nullptr);
        merge_kernel<<<N_TOK / 4, 256, 0, stream>>>(pO, pl, out, nsplit);
    } else {
        flash_kernel<<<dim3(N_TOK / 128, 1), 256, 0, stream>>>(
            Q, K, Vt, u32, N_TOK, nullptr, nullptr, out);
    }
}